// Round 5
// baseline (1980.978 us; speedup 1.0000x reference)
//
#include <hip/hip_runtime.h>

#define T_STEPS 31
#define CIN     64
#define COUT    512
#define WSLEN   512
#define KSZ     32
#define CSTRIDE 16
#define KRED    2048                 // CIN*KSZ
#define NBATCH  1024
#define BCHUNK  512                  // batch rows per pass (seq buffer reuse)
#define MCHUNK  (BCHUNK * T_STEPS)   // 15872 rows per pass
#define NKT     (KRED / 16)          // 128 K-tiles

__device__ __forceinline__ double clip01d(double v) { return fmin(fmax(v, 0.0), 1.0); }

// ---------------------------------------------------------------------------
// Prep: transpose conv_w [co][ci][k] -> wT [r=ci*32+k][co]   (f32, exact)
//       transpose fc1_w  [co][c]     -> fc1wT [c][co]        (f32, exact)
// ---------------------------------------------------------------------------
__global__ __launch_bounds__(256) void prep_kernel(
    const float* __restrict__ conv_w, const float* __restrict__ fc1_w,
    float* __restrict__ wT, float* __restrict__ fc1wT)
{
    int idx = blockIdx.x * 256 + threadIdx.x;
    int co = idx & 511;
    int r  = idx >> 9;
    if (idx < KRED * COUT)  wT[idx]    = conv_w[co * KRED + r];
    if (idx < COUT * COUT)  fc1wT[idx] = fc1_w[co * COUT + r];
}

// ---------------------------------------------------------------------------
// Conv1d + BN, f64 VALU v2: double-buffered LDS (1 barrier/K-tile) and
// conflict-free micro-tile column mapping {tx, tx+16, tx+32, tx+48}.
// M = MCHUNK rows (b,t), N = 512 (co), K = 2048. BM=BN=64, BK=16.
// ---------------------------------------------------------------------------
__global__ __launch_bounds__(256) void conv_bn_f64_v2_kernel(
    const float* __restrict__ x, const float* __restrict__ wT,
    const float* __restrict__ conv_b,
    const float* __restrict__ bn_gamma, const float* __restrict__ bn_beta,
    const float* __restrict__ bn_mean,  const float* __restrict__ bn_var,
    double* __restrict__ seq, int b_base)
{
    __shared__ double As[2][16][64];   // [buf][k][m]
    __shared__ double Bs[2][16][64];   // [buf][k][n]

    const int tid = threadIdx.x;
    const int nMB = MCHUNK / 64;           // 248
    const int bm = blockIdx.x % nMB;
    const int bn = blockIdx.x / nMB;
    const int m0 = bm * 64, n0 = bn * 64;

    // staging maps
    const int miA = tid & 63;
    const int kqA = tid >> 6;              // 0..3
    const int mA  = m0 + miA;
    const int bA  = b_base + mA / T_STEPS;
    const int tA  = mA % T_STEPS;
    const float* xp = x + (size_t)bA * CIN * WSLEN + tA * CSTRIDE;
    const int rB  = tid >> 4;              // 0..15
    const int nqB = tid & 15;

    // micro-tile map: rows ty*4+{0..3}, cols tx+{0,16,32,48}
    const int tx = tid & 15, ty = tid >> 4;

    double acc[4][4] = {};                 // [row i][col group c]

    // ---- prologue: stage tile 0 ----
    {
        float4 a = *(const float4*)(xp + kqA * 4);                       // it=0: ci=0, ks=0
        float4 b = *(const float4*)(wT + (size_t)rB * COUT + n0 + nqB * 4);
        As[0][kqA * 4 + 0][miA] = (double)a.x;
        As[0][kqA * 4 + 1][miA] = (double)a.y;
        As[0][kqA * 4 + 2][miA] = (double)a.z;
        As[0][kqA * 4 + 3][miA] = (double)a.w;
        Bs[0][rB][nqB * 4 + 0] = (double)b.x;
        Bs[0][rB][nqB * 4 + 1] = (double)b.y;
        Bs[0][rB][nqB * 4 + 2] = (double)b.z;
        Bs[0][rB][nqB * 4 + 3] = (double)b.w;
    }
    __syncthreads();

    for (int it = 0; it < NKT; ++it) {
        const int cur = it & 1;

        // issue next tile's global loads early (latency hides under compute)
        float4 a2, b2;
        const bool more = (it + 1 < NKT);
        if (more) {
            const int kt = (it + 1) * 16;
            a2 = *(const float4*)(xp + (kt >> 5) * WSLEN + (kt & 31) + kqA * 4);
            b2 = *(const float4*)(wT + (size_t)(kt + rB) * COUT + n0 + nqB * 4);
        }

        #pragma unroll
        for (int kk = 0; kk < 16; ++kk) {
            double av[4];
            *(double2*)&av[0] = *(const double2*)&As[cur][kk][ty * 4 + 0];
            *(double2*)&av[2] = *(const double2*)&As[cur][kk][ty * 4 + 2];
            double bv0 = Bs[cur][kk][tx];
            double bv1 = Bs[cur][kk][tx + 16];
            double bv2 = Bs[cur][kk][tx + 32];
            double bv3 = Bs[cur][kk][tx + 48];
            #pragma unroll
            for (int i = 0; i < 4; ++i) {
                acc[i][0] = fma(av[i], bv0, acc[i][0]);
                acc[i][1] = fma(av[i], bv1, acc[i][1]);
                acc[i][2] = fma(av[i], bv2, acc[i][2]);
                acc[i][3] = fma(av[i], bv3, acc[i][3]);
            }
        }

        if (more) {
            const int nxt = cur ^ 1;
            As[nxt][kqA * 4 + 0][miA] = (double)a2.x;
            As[nxt][kqA * 4 + 1][miA] = (double)a2.y;
            As[nxt][kqA * 4 + 2][miA] = (double)a2.z;
            As[nxt][kqA * 4 + 3][miA] = (double)a2.w;
            Bs[nxt][rB][nqB * 4 + 0] = (double)b2.x;
            Bs[nxt][rB][nqB * 4 + 1] = (double)b2.y;
            Bs[nxt][rB][nqB * 4 + 2] = (double)b2.z;
            Bs[nxt][rB][nqB * 4 + 3] = (double)b2.w;
        }
        __syncthreads();
    }

    // ---- epilogue: conv bias + BN in f64, store double ----
    #pragma unroll
    for (int c = 0; c < 4; ++c) {
        const int n = n0 + tx + 16 * c;
        double g  = (double)bn_gamma[n];
        double be = (double)bn_beta[n];
        double mn = (double)bn_mean[n];
        double vr = (double)bn_var[n];
        double cb = (double)conv_b[n];
        double inv = 1.0 / sqrt(vr + 1e-5);
        #pragma unroll
        for (int i = 0; i < 4; ++i) {
            int m = m0 + ty * 4 + i;
            seq[(size_t)m * COUT + n] = g * (acc[i][c] + cb - mn) * inv + be;
        }
    }
}

// ---------------------------------------------------------------------------
// SNN scan v3 (unchanged): 1 batch row per block, 512 threads.
// ---------------------------------------------------------------------------
__global__ __launch_bounds__(512, 4) void snn_scan_v3_kernel(
    const double* __restrict__ seq, const float* __restrict__ fc1wT,
    const float* __restrict__ fc1_b, const float* __restrict__ fc2_w,
    const float* __restrict__ fc2_b, const float* __restrict__ beta_enc,
    const float* __restrict__ beta_hid, const float* __restrict__ beta_out,
    float* __restrict__ out, int b_base)
{
    __shared__ int   list[COUT];
    __shared__ int   wcnt[8];
    __shared__ double red[8][2];

    const int tid  = threadIdx.x;
    const int lane = tid & 63;
    const int wave = tid >> 6;
    const int row  = blockIdx.x;
    const int brow = b_base + row;

    const double be  = clip01d((double)beta_enc[tid]);
    const double bh  = clip01d((double)beta_hid[tid]);
    const double f1b = (double)fc1_b[tid];
    const double w2a = (double)fc2_w[tid];
    const double w2b = (double)fc2_w[COUT + tid];

    double bo = 0.0, f2b = 0.0, om = 0.0;
    if (tid < 2) { bo = clip01d((double)beta_out[tid]); f2b = (double)fc2_b[tid]; }

    double em = 0.0, hm = 0.0;
    const double* sp = seq + (size_t)row * T_STEPS * COUT + tid;

    for (int t = 0; t < T_STEPS; ++t) {
        double inp = sp[(size_t)t * COUT];
        double e = be * em + inp - ((em > 1.0) ? 1.0 : 0.0);
        em = e;
        bool spike = (e > 1.0);

        unsigned long long mask = __ballot(spike);
        if (lane == 0) wcnt[wave] = __popcll(mask);
        __syncthreads();

        int base = 0, cnt = 0;
        #pragma unroll
        for (int w = 0; w < 8; ++w) {
            int v = wcnt[w];
            base += (w < wave) ? v : 0;
            cnt  += v;
        }
        if (spike) {
            int pos = base + __popcll(mask & ((1ull << lane) - 1ull));
            list[pos] = tid;
        }
        __syncthreads();

        double s0 = 0.0, s1 = 0.0, s2 = 0.0, s3 = 0.0;
        const float* fw = fc1wT + tid;
        int i = 0;
        for (; i + 4 <= cnt; i += 4) {
            int cA = list[i], cB = list[i + 1], cC = list[i + 2], cD = list[i + 3];
            float wA = fw[(size_t)cA * COUT];
            float wB = fw[(size_t)cB * COUT];
            float wC = fw[(size_t)cC * COUT];
            float wD = fw[(size_t)cD * COUT];
            s0 += (double)wA;
            s1 += (double)wB;
            s2 += (double)wC;
            s3 += (double)wD;
        }
        for (; i < cnt; ++i) s0 += (double)fw[(size_t)list[i] * COUT];
        double cur1 = ((s0 + s1) + (s2 + s3)) + f1b;

        double h = bh * hm + cur1 - ((hm > 1.0) ? 1.0 : 0.0);
        hm = h;
        double sh = (h > 1.0) ? 1.0 : 0.0;
        double p0 = sh * w2a;
        double p1 = sh * w2b;
        #pragma unroll
        for (int off = 32; off > 0; off >>= 1) {
            p0 += __shfl_down(p0, off);
            p1 += __shfl_down(p1, off);
        }
        if (lane == 0) { red[wave][0] = p0; red[wave][1] = p1; }
        __syncthreads();

        if (tid < 2) {
            double cur2 = f2b;
            #pragma unroll
            for (int w = 0; w < 8; ++w) cur2 += red[w][tid];
            double o = bo * om + cur2 - ((om > 1.0) ? 1.0 : 0.0);
            om = o;
            float so = (o > 1.0) ? 1.0f : 0.0f;
            int bidx = brow * 2 + tid;
            out[2048 + t * 2048 + bidx] = so;               // spk_rec
            out[2048 + 63488 + t * 2048 + bidx] = (float)o; // mem_rec
            if (t == T_STEPS - 1) out[bidx] = (float)o;     // final om
        }
    }
}

// ---------------------------------------------------------------------------
extern "C" void kernel_launch(void* const* d_in, const int* in_sizes, int n_in,
                              void* d_out, int out_size, void* d_ws, size_t ws_size,
                              hipStream_t stream)
{
    const float* x        = (const float*)d_in[0];
    const float* conv_w   = (const float*)d_in[1];
    const float* conv_b   = (const float*)d_in[2];
    const float* bn_gamma = (const float*)d_in[3];
    const float* bn_beta  = (const float*)d_in[4];
    const float* bn_mean  = (const float*)d_in[5];
    const float* bn_var   = (const float*)d_in[6];
    const float* fc1_w    = (const float*)d_in[7];
    const float* fc1_b    = (const float*)d_in[8];
    const float* fc2_w    = (const float*)d_in[9];
    const float* fc2_b    = (const float*)d_in[10];
    const float* beta_enc = (const float*)d_in[11];
    const float* beta_hid = (const float*)d_in[12];
    const float* beta_out = (const float*)d_in[13];
    float* out = (float*)d_out;

    float*  wT    = (float*)d_ws;                       // [2048][512] f32, 4 MB
    float*  fc1wT = wT + (size_t)KRED * COUT;           // [512][512]  f32, 1 MB
    double* seq   = (double*)(fc1wT + (size_t)COUT * COUT); // [15872][512] f64, 65 MB

    prep_kernel<<<4096, 256, 0, stream>>>(conv_w, fc1_w, wT, fc1wT);

    for (int chunk = 0; chunk < 2; ++chunk) {
        int b_base = chunk * BCHUNK;
        conv_bn_f64_v2_kernel<<<(MCHUNK / 64) * (COUT / 64), 256, 0, stream>>>(
            x, wT, conv_b, bn_gamma, bn_beta, bn_mean, bn_var, seq, b_base);
        snn_scan_v3_kernel<<<BCHUNK, 512, 0, stream>>>(
            seq, fc1wT, fc1_b, fc2_w, fc2_b, beta_enc, beta_hid, beta_out, out, b_base);
    }
}